// Round 3
// baseline (129.636 us; speedup 1.0000x reference)
//
#include <hip/hip_runtime.h>

// Problem constants: B=4, T=1024, F=500, H=128, P=64
// All external buffers fp32. Internal GEMMs bf16 (fp32 MFMA accum).
// out = [probs (B*T*P=262144), all_states (T*B*H=524288)] fp32
//
// ws layout:
//   gi_bf   [0,        3145728)  4096x384 bf16
//   S_bf    [3145728,  4194304)  4096x128 bf16 ([T,B,H] rows sr=t*4+b)
//   WcT     [4194304,  6291456)  64x16x128x8 bf16 (folded ctx weights,
//                                k-chunk-major: [p][kc][n][8k])
//   partial [6291456, 23068672)  8 x 4096x128 fp32 (ctx split-K partials)

typedef short bf16x8 __attribute__((ext_vector_type(8)));
typedef float f32x4 __attribute__((ext_vector_type(4)));
typedef float f32x16 __attribute__((ext_vector_type(16)));
typedef unsigned short u16;
typedef unsigned int u32;

__device__ __forceinline__ float bf2f(u16 u) {
  union { u32 i; float f; } v; v.i = ((u32)u) << 16; return v.f;
}
__device__ __forceinline__ u16 f2bf(float f) {
  union { float f; u32 i; } v; v.f = f;
  u32 u = v.i;
  return (u16)((u + 0x7FFFu + ((u >> 16) & 1u)) >> 16);
}
__device__ __forceinline__ u32 pack2(float a, float b) {
  return (u32)f2bf(a) | ((u32)f2bf(b) << 16);
}
__device__ __forceinline__ float sigmoidf_(float x) {
  return 1.0f / (1.0f + __expf(-x));
}

// Fused front kernel: blocks 0..191 run the gi GEMM (bx = bid%64, by = bid/64),
// blocks 192..319 run the W_ctx prep (hp = bid-192). Roles share one 48 KB
// LDS byte array (manual overlay) so gi keeps its occupancy. No data
// dependence between roles -> legal single dispatch.
//
// gi role: gi = x @ W_ih^T (M=4096, N=384, K=500 zero-pad 512). 512 thr
//   (8 waves, 2x4, wave-tile 32x32), block 64x128, BK=64, dbuf XOR-swizzled.
// prep role: WcT[((p*16+(h>>3))*128+h')*8+(h&7)] = W_ctx[h', 8192+h*64+p]
//   (+ part1 row sums folded into p==0). k-chunk-major so ctx 32x32 MFMA
//   B-fragments are 512-B coalesced.
__global__ __launch_bounds__(512, 4) void k_front(const float* __restrict__ x,
                                                  const float* __restrict__ W_ih,
                                                  u16* __restrict__ gi_bf,
                                                  const float* __restrict__ W_ctx,
                                                  u16* __restrict__ WcT) {
  __shared__ __align__(16) char smem[49152];
  const int tid = threadIdx.x;
  const int bid = blockIdx.x;

  if (bid < 192) {
    // ---------------- gi GEMM role ----------------
    typedef u16 AsmT[64][64];
    typedef u16 BsmT[128][64];
    AsmT* Asm = (AsmT*)smem;              // [2][64][64]  = 16 KB
    BsmT* Bsm = (BsmT*)(smem + 16384);    // [2][128][64] = 32 KB
    const int w = tid >> 6, lane = tid & 63;
    const int l15 = lane & 15, quad = lane >> 4;
    const int wm = (w & 1) * 32, wn = (w >> 1) * 32;
    const int m0 = (bid & 63) * 64;
    const int n0 = (bid >> 6) * 128;
    f32x4 acc[2][2];
    for (int i = 0; i < 2; ++i)
      for (int j = 0; j < 2; ++j) acc[i][j] = (f32x4){0.f, 0.f, 0.f, 0.f};

    uint4 ra, rb[2];
    auto cvt_load = [](const float* base, int k) -> uint4 {
      float4 a = make_float4(0.f, 0.f, 0.f, 0.f), b = a;
      if (k < 500)     a = *(const float4*)(base + k);
      if (k + 4 < 500) b = *(const float4*)(base + k + 4);
      uint4 o; o.x = pack2(a.x, a.y); o.y = pack2(a.z, a.w);
      o.z = pack2(b.x, b.y); o.w = pack2(b.z, b.w);
      return o;
    };
    auto load_step = [&](int s) {
      int kc = s * 64;
      {   // A: 64 rows x 8 chunks = 512, 1/thread
        int c = tid;
        ra = cvt_load(x + (size_t)(m0 + (c >> 3)) * 500, kc + (c & 7) * 8);
      }
#pragma unroll
      for (int j = 0; j < 2; ++j) {   // B: 128 rows x 8 chunks = 1024, 2/thread
        int c = j * 512 + tid;
        rb[j] = cvt_load(W_ih + (size_t)(n0 + (c >> 3)) * 500, kc + (c & 7) * 8);
      }
    };
    auto write_step = [&](int b) {
      {
        int c = tid;
        int r = c >> 3, pc = (c & 7) ^ (r & 7);
        *(uint4*)&Asm[b][r][pc * 8] = ra;
      }
#pragma unroll
      for (int j = 0; j < 2; ++j) {
        int c = j * 512 + tid;
        int r = c >> 3, pc = (c & 7) ^ (r & 7);
        *(uint4*)&Bsm[b][r][pc * 8] = rb[j];
      }
    };

    load_step(0); write_step(0); __syncthreads();
    for (int s = 0; s < 8; ++s) {
      int cur = s & 1;
      if (s < 7) load_step(s + 1);
#pragma unroll
      for (int kk = 0; kk < 2; ++kk) {
        int ch = kk * 4 + quad;
        bf16x8 af[2], bfr[2];
#pragma unroll
        for (int mt = 0; mt < 2; ++mt) {
          int r = wm + mt * 16 + l15;
          af[mt] = *(const bf16x8*)&Asm[cur][r][(ch ^ (r & 7)) * 8];
        }
#pragma unroll
        for (int nt = 0; nt < 2; ++nt) {
          int r = wn + nt * 16 + l15;
          bfr[nt] = *(const bf16x8*)&Bsm[cur][r][(ch ^ (r & 7)) * 8];
        }
#pragma unroll
        for (int mt = 0; mt < 2; ++mt)
#pragma unroll
          for (int nt = 0; nt < 2; ++nt)
            acc[mt][nt] = __builtin_amdgcn_mfma_f32_16x16x32_bf16(af[mt], bfr[nt], acc[mt][nt], 0, 0, 0);
      }
      if (s < 7) write_step((s + 1) & 1);
      __syncthreads();
    }
    for (int mt = 0; mt < 2; ++mt)
      for (int nt = 0; nt < 2; ++nt)
        for (int rg = 0; rg < 4; ++rg) {
          int m = m0 + wm + mt * 16 + quad * 4 + rg;   // C/D: row=(lane>>4)*4+reg
          int n = n0 + wn + nt * 16 + l15;             //      col=lane&15
          gi_bf[m * 384 + n] = f2bf(acc[mt][nt][rg]);
        }
  } else {
    // ---------------- prep role ----------------
    typedef float T2Row[68];
    T2Row* t2 = (T2Row*)smem;                 // [128][68] = 34816 B
    float* s1 = (float*)(smem + 34816);       // 512 B
    const int hp = bid - 192;
    const float* wrow = W_ctx + hp * 16384;
    // part2 -> LDS transpose buffer (2048 float4 / 512 thr = 4 iters)
    for (int it = 0; it < 4; ++it) {
      int i = it * 512 + tid;
      int j = i * 4;
      int h = j >> 6, q = j & 63;
      *(float4*)&t2[h][q] = *(const float4*)(wrow + 8192 + j);
    }
    // part1 row sums via wave reduce: wave w handles rows w, w+8, ...
    {
      const int w = tid >> 6, lane = tid & 63;
      for (int rr = w; rr < 128; rr += 8) {
        float v = wrow[rr * 64 + lane];
#pragma unroll
        for (int off = 32; off; off >>= 1) v += __shfl_down(v, off, 64);
        if (lane == 0) s1[rr] = v;
      }
    }
    __syncthreads();
    // store: 2048 (p, h0) pairs / 512 thr = 4 iters
    for (int it = 0; it < 4; ++it) {
      int i = it * 512 + tid;
      int p = i >> 5, h0 = (i & 31) * 4;
      float v0 = t2[h0 + 0][p], v1 = t2[h0 + 1][p];
      float v2 = t2[h0 + 2][p], v3 = t2[h0 + 3][p];
      if (p == 0) { v0 += s1[h0]; v1 += s1[h0 + 1]; v2 += s1[h0 + 2]; v3 += s1[h0 + 3]; }
      uint2 o; o.x = pack2(v0, v1); o.y = pack2(v2, v3);
      *(uint2*)(WcT + ((size_t)(p * 16 + (h0 >> 3)) * 128 + hp) * 8 + (h0 & 7)) = o;
    }
  }
}

// GRU gates with h=0: s = (1-sig(gz+bz)) * tanh(gn + sig(gr+br)*bn_hh).
// Vectorized x4 over h (uint2 bf16 loads, float4 stores).
__global__ void k_states(const u16* __restrict__ gi_bf,
                         const float* __restrict__ b_ih, const float* __restrict__ b_hh,
                         u16* __restrict__ S_bf, float* __restrict__ out_states) {
  int g = blockIdx.x * 256 + threadIdx.x;  // 131072 = 4096 rows x 32 h-groups
  int r = g >> 5, h0 = (g & 31) * 4;
  const u16* gr = gi_bf + r * 384;
  uint2 ur = *(const uint2*)(gr + h0);
  uint2 uz = *(const uint2*)(gr + 128 + h0);
  uint2 un = *(const uint2*)(gr + 256 + h0);
  float4 bir = *(const float4*)(b_ih + h0);
  float4 biz = *(const float4*)(b_ih + 128 + h0);
  float4 bin = *(const float4*)(b_ih + 256 + h0);
  float4 bhr = *(const float4*)(b_hh + h0);
  float4 bhz = *(const float4*)(b_hh + 128 + h0);
  float4 bhn = *(const float4*)(b_hh + 256 + h0);
  float xr[4] = { bf2f((u16)ur.x) + bir.x + bhr.x, bf2f((u16)(ur.x >> 16)) + bir.y + bhr.y,
                  bf2f((u16)ur.y) + bir.z + bhr.z, bf2f((u16)(ur.y >> 16)) + bir.w + bhr.w };
  float xz[4] = { bf2f((u16)uz.x) + biz.x + bhz.x, bf2f((u16)(uz.x >> 16)) + biz.y + bhz.y,
                  bf2f((u16)uz.y) + biz.z + bhz.z, bf2f((u16)(uz.y >> 16)) + biz.w + bhz.w };
  float xn[4] = { bf2f((u16)un.x) + bin.x, bf2f((u16)(un.x >> 16)) + bin.y,
                  bf2f((u16)un.y) + bin.z, bf2f((u16)(un.y >> 16)) + bin.w };
  float bn[4] = { bhn.x, bhn.y, bhn.z, bhn.w };
  float s[4];
#pragma unroll
  for (int j = 0; j < 4; ++j) {
    float rg = sigmoidf_(xr[j]);
    float zg = sigmoidf_(xz[j]);
    float n = tanhf(xn[j] + rg * bn[j]);
    s[j] = (1.f - zg) * n;
  }
  int b = r >> 10, t = r & 1023;
  size_t o = (size_t)(t * 4 + b) * 128 + h0;
  uint2 sb; sb.x = pack2(s[0], s[1]); sb.y = pack2(s[2], s[3]);
  *(uint2*)(S_bf + o) = sb;
  float4 so = make_float4(s[0], s[1], s[2], s[3]);
  *(float4*)(out_states + o) = so;
}

// Context GEMM v4: partial[chunk][m][h'] = sum_{p in chunk of 8} Wc_p @ s[max(t-p,0),b].
// 32x32x16 MFMA, wave-tile 64m x 64n -> per (p,ks): 2 A ds_reads + 2 B global
// loads feed FOUR MFMAs (0.5 LDS reads/MFMA, 0.5 B loads/MFMA; v3 had 0.5/1.0).
// Halves the L2 B-traffic (268 -> 134 MB). Grid (64 m-tiles, 8 p-chunks) = 512
// blocks, 128 threads (2 waves side by side in n), block 64m x 128n, 2
// blocks/CU. A window (92 rows, 23.5 KB, 4-bit XOR swizzle pos = kc^(r&15))
// staged once; B (WcT, L2-resident) straight to registers, 512-B coalesced.
// ZERO barriers in the K-loop (fully unrolled; compiler pipelines loads).
// A frag (32x32x16): lane l = row l&31, k = (l>>5)*8+j; B: col l&31, same k.
// C/D: col = lane&31, row = (reg&3) + 8*(reg>>2) + 4*(lane>>5).
__global__ __launch_bounds__(128, 2) void k_gemm_ctx(const u16* __restrict__ S_bf,
                                                     const u16* __restrict__ WcT,
                                                     float* __restrict__ partial) {
  __shared__ u16 Awin[92][128];     // [window row][16 swizzled 16-B chunks]
  const int tid = threadIdx.x;
  const int w = tid >> 6, lane = tid & 63;
  const int l31 = lane & 31, half = lane >> 5;
  const int wn = w * 64;
  const int m0 = blockIdx.x * 64;
  const int P0 = blockIdx.y * 8;
  const int tlo = (m0 >> 2) - P0 - 7;   // may be negative; rows clamp to s[0]
  f32x16 acc[2][2];                 // [mt][nt]
#pragma unroll
  for (int i = 0; i < 16; ++i) {
    acc[0][0][i] = 0.f; acc[0][1][i] = 0.f;
    acc[1][0][i] = 0.f; acc[1][1][i] = 0.f;
  }

  // Stage A window: row r holds s[max(tlo + (r>>2), 0), b=r&3][:].
  for (int it = 0; it < 12; ++it) {
    int idx = it * 128 + tid;       // 92 rows x 16 chunks = 1472
    if (idx < 1472) {
      int r = idx >> 4, ch = idx & 15;
      int t = tlo + (r >> 2); if (t < 0) t = 0;
      uint4 v = *(const uint4*)(S_bf + (size_t)(t * 4 + (r & 3)) * 128 + ch * 8);
      *(uint4*)&Awin[r][((ch ^ (r & 15)) & 15) * 8] = v;
    }
  }
  __syncthreads();                  // the ONLY barrier

  // Per-lane B base (k-chunk-major WcT): chunk addr =
  // ((p*16 + ks*2 + half)*128 + wn + nt*32 + l31)*8.
  const u16* wbase = WcT + (size_t)half * 1024 + (size_t)(wn + l31) * 8;
#pragma unroll
  for (int pi = 0; pi < 8; ++pi) {
    const int shift = 4 * (7 - pi);               // A window row offset
    const u16* wp = wbase + (size_t)((P0 + pi) * 16) * 1024;
#pragma unroll
    for (int ks = 0; ks < 8; ++ks) {              // K = 128 = 8 steps of 16
      bf16x8 bfr[2];
      bfr[0] = *(const bf16x8*)(wp + (size_t)(ks * 2) * 1024);
      bfr[1] = *(const bf16x8*)(wp + (size_t)(ks * 2) * 1024 + 256);
      int kc = ks * 2 + half;
      bf16x8 af[2];
#pragma unroll
      for (int mt = 0; mt < 2; ++mt) {
        int r = mt * 32 + shift + l31;            // max 91
        af[mt] = *(const bf16x8*)&Awin[r][((kc ^ (r & 15)) & 15) * 8];
      }
#pragma unroll
      for (int mt = 0; mt < 2; ++mt)
#pragma unroll
        for (int nt = 0; nt < 2; ++nt)
          acc[mt][nt] = __builtin_amdgcn_mfma_f32_32x32x16_bf16(af[mt], bfr[nt], acc[mt][nt], 0, 0, 0);
    }
  }
  float* op = partial + (size_t)blockIdx.y * 524288;
#pragma unroll
  for (int mt = 0; mt < 2; ++mt)
#pragma unroll
    for (int nt = 0; nt < 2; ++nt)
#pragma unroll
      for (int rg = 0; rg < 16; ++rg) {
        int m = m0 + mt * 32 + (rg & 3) + 8 * (rg >> 2) + 4 * half;
        int n = wn + nt * 32 + l31;
        op[m * 128 + n] = acc[mt][nt][rg];
      }
}

// Reduce 8 partials + b_ctx -> sigmoid gate; gated = states(fp32)*gate; FC+sig+clip.
// v3: 16 rows/block (halves W_fc staging traffic), float4 partial reads,
// W_fc staged [pp][h] chunk-XOR-swizzled, dot loop all-b128.
__global__ __launch_bounds__(256) void k_epilogue(const float* __restrict__ partial,
                                                  const float* __restrict__ states,
                                                  const float* __restrict__ b_ctx,
                                                  const float* __restrict__ W_fc,
                                                  const float* __restrict__ b_fc,
                                                  float* __restrict__ out_probs) {
  __shared__ float Wfc2[64][128];   // chunk c of row pp at pos c ^ (pp&31)
  __shared__ float gated[16][128];
  const int tid = threadIdx.x;
  const int row0 = blockIdx.x * 16;
  for (int it = 0; it < 8; ++it) {
    int i = it * 256 + tid;         // 64 rows x 32 float4 chunks
    int pp = i >> 5, c = i & 31;
    float4 v = *(const float4*)(W_fc + i * 4);
    *(float4*)&Wfc2[pp][((c ^ pp) & 31) * 4] = v;
  }
  for (int it = 0; it < 2; ++it) {
    int i = it * 256 + tid;         // 16 rows x 32 h-chunks = 512
    int lr = i >> 5, h0 = (i & 31) * 4;
    int sr = row0 + lr;
    float4 gp = *(const float4*)(b_ctx + h0);
#pragma unroll
    for (int c = 0; c < 8; ++c) {
      float4 pv = *(const float4*)(partial + (size_t)c * 524288 + (size_t)sr * 128 + h0);
      gp.x += pv.x; gp.y += pv.y; gp.z += pv.z; gp.w += pv.w;
    }
    float4 st = *(const float4*)(states + (size_t)sr * 128 + h0);
    float4 gv;
    gv.x = st.x * sigmoidf_(gp.x);
    gv.y = st.y * sigmoidf_(gp.y);
    gv.z = st.z * sigmoidf_(gp.z);
    gv.w = st.w * sigmoidf_(gp.w);
    *(float4*)&gated[lr][h0] = gv;
  }
  __syncthreads();
  for (int it = 0; it < 4; ++it) {
    int o = it * 256 + tid;         // 16 rows x 64 pp = 1024
    int lr = o >> 6, pp = o & 63;
    int sr = row0 + lr;
    float dot = 0.f;
#pragma unroll
    for (int i = 0; i < 32; ++i) {
      float4 g = *(const float4*)&gated[lr][i * 4];
      float4 wv = *(const float4*)&Wfc2[pp][((i ^ pp) & 31) * 4];
      dot += g.x * wv.x + g.y * wv.y + g.z * wv.z + g.w * wv.w;
    }
    float pv = sigmoidf_(dot + b_fc[pp]);
    pv = (pv > 0.001f) ? pv : 0.001f;
    pv = (pv < 0.999f) ? pv : 0.999f;
    int t = sr >> 2, b = sr & 3;
    out_probs[(b * 1024 + t) * 64 + pp] = pv;
  }
}

extern "C" void kernel_launch(void* const* d_in, const int* in_sizes, int n_in,
                              void* d_out, int out_size, void* d_ws, size_t ws_size,
                              hipStream_t stream) {
  const float* x     = (const float*)d_in[0];
  const float* W_ih  = (const float*)d_in[1];
  // d_in[2] = W_hh: unused (hidden state is always 0 in the reference)
  const float* b_ih  = (const float*)d_in[3];
  const float* b_hh  = (const float*)d_in[4];
  const float* W_ctx = (const float*)d_in[5];
  const float* b_ctx = (const float*)d_in[6];
  const float* W_fc  = (const float*)d_in[7];
  const float* b_fc  = (const float*)d_in[8];
  float* out = (float*)d_out;

  char* ws = (char*)d_ws;
  u16*   gi_bf   = (u16*)  (ws + 0);          // 3,145,728 B
  u16*   S_bf    = (u16*)  (ws + 3145728);    // 1,048,576 B
  u16*   WcT     = (u16*)  (ws + 4194304);    // 2,097,152 B
  float* partial = (float*)(ws + 6291456);    // 16,777,216 B
  // total ws used: 23,068,672 bytes

  k_front<<<320, 512, 0, stream>>>(x, W_ih, gi_bf, W_ctx, WcT);
  k_states<<<512, 256, 0, stream>>>(gi_bf, b_ih, b_hh, S_bf, out + 262144);
  k_gemm_ctx<<<dim3(64, 8), 128, 0, stream>>>(S_bf, WcT, partial);
  k_epilogue<<<256, 256, 0, stream>>>(partial, out + 262144, b_ctx, W_fc, b_fc, out);
}

// Round 4
// 120.740 us; speedup vs baseline: 1.0737x; 1.0737x over previous
//
#include <hip/hip_runtime.h>

// Problem constants: B=4, T=1024, F=500, H=128, P=64
// All external buffers fp32. Internal GEMMs bf16 (fp32 MFMA accum).
// out = [probs (B*T*P=262144), all_states (T*B*H=524288)] fp32
//
// ws layout:
//   gi_bf   [0,        3145728)  4096x384 bf16
//   S_bf    [3145728,  4194304)  4096x128 bf16 ([T,B,H] rows sr=t*4+b)
//   WcT     [4194304,  6291456)  64x16x128x8 bf16 (folded ctx weights,
//                                k-chunk-major: [p][kc][n][8k])
//   partial [6291456, 23068672)  8 x 4096x128 fp32 (ctx split-K partials)

typedef short bf16x8 __attribute__((ext_vector_type(8)));
typedef float f32x4 __attribute__((ext_vector_type(4)));
typedef float f32x16 __attribute__((ext_vector_type(16)));
typedef unsigned short u16;
typedef unsigned int u32;

__device__ __forceinline__ float bf2f(u16 u) {
  union { u32 i; float f; } v; v.i = ((u32)u) << 16; return v.f;
}
__device__ __forceinline__ u16 f2bf(float f) {
  union { float f; u32 i; } v; v.f = f;
  u32 u = v.i;
  return (u16)((u + 0x7FFFu + ((u >> 16) & 1u)) >> 16);
}
__device__ __forceinline__ u32 pack2(float a, float b) {
  return (u32)f2bf(a) | ((u32)f2bf(b) << 16);
}
__device__ __forceinline__ float sigmoidf_(float x) {
  return 1.0f / (1.0f + __expf(-x));
}

// Fused front kernel: blocks 0..191 run the gi GEMM (bx = bid%64, by = bid/64),
// blocks 192..319 run the W_ctx prep (hp = bid-192). Roles share one 48 KB
// LDS byte array (manual overlay) so gi keeps its occupancy.
__global__ __launch_bounds__(512, 4) void k_front(const float* __restrict__ x,
                                                  const float* __restrict__ W_ih,
                                                  u16* __restrict__ gi_bf,
                                                  const float* __restrict__ W_ctx,
                                                  u16* __restrict__ WcT) {
  __shared__ __align__(16) char smem[49152];
  const int tid = threadIdx.x;
  const int bid = blockIdx.x;

  if (bid < 192) {
    // ---------------- gi GEMM role ----------------
    typedef u16 AsmT[64][64];
    typedef u16 BsmT[128][64];
    AsmT* Asm = (AsmT*)smem;              // [2][64][64]  = 16 KB
    BsmT* Bsm = (BsmT*)(smem + 16384);    // [2][128][64] = 32 KB
    const int w = tid >> 6, lane = tid & 63;
    const int l15 = lane & 15, quad = lane >> 4;
    const int wm = (w & 1) * 32, wn = (w >> 1) * 32;
    const int m0 = (bid & 63) * 64;
    const int n0 = (bid >> 6) * 128;
    f32x4 acc[2][2];
    for (int i = 0; i < 2; ++i)
      for (int j = 0; j < 2; ++j) acc[i][j] = (f32x4){0.f, 0.f, 0.f, 0.f};

    uint4 ra, rb[2];
    auto cvt_load = [](const float* base, int k) -> uint4 {
      float4 a = make_float4(0.f, 0.f, 0.f, 0.f), b = a;
      if (k < 500)     a = *(const float4*)(base + k);
      if (k + 4 < 500) b = *(const float4*)(base + k + 4);
      uint4 o; o.x = pack2(a.x, a.y); o.y = pack2(a.z, a.w);
      o.z = pack2(b.x, b.y); o.w = pack2(b.z, b.w);
      return o;
    };
    auto load_step = [&](int s) {
      int kc = s * 64;
      {   // A: 64 rows x 8 chunks = 512, 1/thread
        int c = tid;
        ra = cvt_load(x + (size_t)(m0 + (c >> 3)) * 500, kc + (c & 7) * 8);
      }
#pragma unroll
      for (int j = 0; j < 2; ++j) {   // B: 128 rows x 8 chunks = 1024, 2/thread
        int c = j * 512 + tid;
        rb[j] = cvt_load(W_ih + (size_t)(n0 + (c >> 3)) * 500, kc + (c & 7) * 8);
      }
    };
    auto write_step = [&](int b) {
      {
        int c = tid;
        int r = c >> 3, pc = (c & 7) ^ (r & 7);
        *(uint4*)&Asm[b][r][pc * 8] = ra;
      }
#pragma unroll
      for (int j = 0; j < 2; ++j) {
        int c = j * 512 + tid;
        int r = c >> 3, pc = (c & 7) ^ (r & 7);
        *(uint4*)&Bsm[b][r][pc * 8] = rb[j];
      }
    };

    load_step(0); write_step(0); __syncthreads();
    for (int s = 0; s < 8; ++s) {
      int cur = s & 1;
      if (s < 7) load_step(s + 1);
#pragma unroll
      for (int kk = 0; kk < 2; ++kk) {
        int ch = kk * 4 + quad;
        bf16x8 af[2], bfr[2];
#pragma unroll
        for (int mt = 0; mt < 2; ++mt) {
          int r = wm + mt * 16 + l15;
          af[mt] = *(const bf16x8*)&Asm[cur][r][(ch ^ (r & 7)) * 8];
        }
#pragma unroll
        for (int nt = 0; nt < 2; ++nt) {
          int r = wn + nt * 16 + l15;
          bfr[nt] = *(const bf16x8*)&Bsm[cur][r][(ch ^ (r & 7)) * 8];
        }
#pragma unroll
        for (int mt = 0; mt < 2; ++mt)
#pragma unroll
          for (int nt = 0; nt < 2; ++nt)
            acc[mt][nt] = __builtin_amdgcn_mfma_f32_16x16x32_bf16(af[mt], bfr[nt], acc[mt][nt], 0, 0, 0);
      }
      if (s < 7) write_step((s + 1) & 1);
      __syncthreads();
    }
    for (int mt = 0; mt < 2; ++mt)
      for (int nt = 0; nt < 2; ++nt)
        for (int rg = 0; rg < 4; ++rg) {
          int m = m0 + wm + mt * 16 + quad * 4 + rg;   // C/D: row=(lane>>4)*4+reg
          int n = n0 + wn + nt * 16 + l15;             //      col=lane&15
          gi_bf[m * 384 + n] = f2bf(acc[mt][nt][rg]);
        }
  } else {
    // ---------------- prep role ----------------
    typedef float T2Row[68];
    T2Row* t2 = (T2Row*)smem;                 // [128][68] = 34816 B
    float* s1 = (float*)(smem + 34816);       // 512 B
    const int hp = bid - 192;
    const float* wrow = W_ctx + hp * 16384;
    // part2 -> LDS transpose buffer (2048 float4 / 512 thr = 4 iters)
    for (int it = 0; it < 4; ++it) {
      int i = it * 512 + tid;
      int j = i * 4;
      int h = j >> 6, q = j & 63;
      *(float4*)&t2[h][q] = *(const float4*)(wrow + 8192 + j);
    }
    // part1 row sums via wave reduce: wave w handles rows w, w+8, ...
    {
      const int w = tid >> 6, lane = tid & 63;
      for (int rr = w; rr < 128; rr += 8) {
        float v = wrow[rr * 64 + lane];
#pragma unroll
        for (int off = 32; off; off >>= 1) v += __shfl_down(v, off, 64);
        if (lane == 0) s1[rr] = v;
      }
    }
    __syncthreads();
    // store: 2048 (p, h0) pairs / 512 thr = 4 iters
    for (int it = 0; it < 4; ++it) {
      int i = it * 512 + tid;
      int p = i >> 5, h0 = (i & 31) * 4;
      float v0 = t2[h0 + 0][p], v1 = t2[h0 + 1][p];
      float v2 = t2[h0 + 2][p], v3 = t2[h0 + 3][p];
      if (p == 0) { v0 += s1[h0]; v1 += s1[h0 + 1]; v2 += s1[h0 + 2]; v3 += s1[h0 + 3]; }
      uint2 o; o.x = pack2(v0, v1); o.y = pack2(v2, v3);
      *(uint2*)(WcT + ((size_t)(p * 16 + (h0 >> 3)) * 128 + hp) * 8 + (h0 & 7)) = o;
    }
  }
}

// GRU gates with h=0: s = (1-sig(gz+bz)) * tanh(gn + sig(gr+br)*bn_hh).
// Vectorized x4 over h (uint2 bf16 loads, float4 stores).
__global__ void k_states(const u16* __restrict__ gi_bf,
                         const float* __restrict__ b_ih, const float* __restrict__ b_hh,
                         u16* __restrict__ S_bf, float* __restrict__ out_states) {
  int g = blockIdx.x * 256 + threadIdx.x;  // 131072 = 4096 rows x 32 h-groups
  int r = g >> 5, h0 = (g & 31) * 4;
  const u16* gr = gi_bf + r * 384;
  uint2 ur = *(const uint2*)(gr + h0);
  uint2 uz = *(const uint2*)(gr + 128 + h0);
  uint2 un = *(const uint2*)(gr + 256 + h0);
  float4 bir = *(const float4*)(b_ih + h0);
  float4 biz = *(const float4*)(b_ih + 128 + h0);
  float4 bin = *(const float4*)(b_ih + 256 + h0);
  float4 bhr = *(const float4*)(b_hh + h0);
  float4 bhz = *(const float4*)(b_hh + 128 + h0);
  float4 bhn = *(const float4*)(b_hh + 256 + h0);
  float xr[4] = { bf2f((u16)ur.x) + bir.x + bhr.x, bf2f((u16)(ur.x >> 16)) + bir.y + bhr.y,
                  bf2f((u16)ur.y) + bir.z + bhr.z, bf2f((u16)(ur.y >> 16)) + bir.w + bhr.w };
  float xz[4] = { bf2f((u16)uz.x) + biz.x + bhz.x, bf2f((u16)(uz.x >> 16)) + biz.y + bhz.y,
                  bf2f((u16)uz.y) + biz.z + bhz.z, bf2f((u16)(uz.y >> 16)) + biz.w + bhz.w };
  float xn[4] = { bf2f((u16)un.x) + bin.x, bf2f((u16)(un.x >> 16)) + bin.y,
                  bf2f((u16)un.y) + bin.z, bf2f((u16)(un.y >> 16)) + bin.w };
  float bn[4] = { bhn.x, bhn.y, bhn.z, bhn.w };
  float s[4];
#pragma unroll
  for (int j = 0; j < 4; ++j) {
    float rg = sigmoidf_(xr[j]);
    float zg = sigmoidf_(xz[j]);
    float n = tanhf(xn[j] + rg * bn[j]);
    s[j] = (1.f - zg) * n;
  }
  int b = r >> 10, t = r & 1023;
  size_t o = (size_t)(t * 4 + b) * 128 + h0;
  uint2 sb; sb.x = pack2(s[0], s[1]); sb.y = pack2(s[2], s[3]);
  *(uint2*)(S_bf + o) = sb;
  float4 so = make_float4(s[0], s[1], s[2], s[3]);
  *(float4*)(out_states + o) = so;
}

// Context GEMM v5: partial[chunk][m][h'] = sum_{p in chunk of 8} Wc_p @ s[max(t-p,0),b].
// 32x32x16 MFMA, wave-tile 64m x 64n (0.5 ds_read/MFMA, 0.5 KB B-load/MFMA;
// total B-traffic 134 MB L2). v4's mistake: 128-thr blocks -> 1 wave/SIMD ->
// L2/LDS latency exposed. v5: 256 thr (4 waves): wave w = p-sub-half (w&1,
// 4 p's) x n-half (w>>1). Each wave runs a 32-iteration barrier-free K-loop,
// then wave pairs reduce their fp32 accs via LDS (2-way-free scalar exchange)
// and the ph=1 wave stores the chunk partial -> same 8-chunk partial layout.
// Grid (64 m-tiles, 8 p-chunks) = 512 blocks, 2 blocks/CU, 8 waves/CU
// (2/SIMD). LDS = union(A-window 23.5 KB, reduce scratch 32 KB) = 32 KB.
// A frag (32x32x16): lane l = row l&31, k = (l>>5)*8+j; B: col l&31, same k.
// C/D: col = lane&31, row = (reg&3) + 8*(reg>>2) + 4*(lane>>5).
__global__ __launch_bounds__(256, 2) void k_gemm_ctx(const u16* __restrict__ S_bf,
                                                     const u16* __restrict__ WcT,
                                                     float* __restrict__ partial) {
  __shared__ __align__(16) char smem[32768];
  u16 (*Awin)[128] = (u16(*)[128])smem;          // [92][128] u16 = 23552 B
  float (*S2)[64][64] = (float(*)[64][64])smem;  // [2][64][64] f32 = 32768 B
  const int tid = threadIdx.x;
  const int w = tid >> 6, lane = tid & 63;
  const int l31 = lane & 31, half = lane >> 5;
  const int ph = w & 1;             // p-sub-half: 4 p's
  const int nh = w >> 1;            // n-half: 64 cols
  const int m0 = blockIdx.x * 64;
  const int P0 = blockIdx.y * 8;
  const int tlo = (m0 >> 2) - P0 - 7;   // may be negative; rows clamp to s[0]
  f32x16 acc[2][2];                 // [mt][nt]
#pragma unroll
  for (int i = 0; i < 16; ++i) {
    acc[0][0][i] = 0.f; acc[0][1][i] = 0.f;
    acc[1][0][i] = 0.f; acc[1][1][i] = 0.f;
  }

  // Stage A window: row r holds s[max(tlo + (r>>2), 0), b=r&3][:], swizzled
  // chunk pos = ch ^ (r & 15).
  for (int it = 0; it < 6; ++it) {
    int idx = it * 256 + tid;       // 92 rows x 16 chunks = 1472
    if (idx < 1472) {
      int r = idx >> 4, ch = idx & 15;
      int t = tlo + (r >> 2); if (t < 0) t = 0;
      uint4 v = *(const uint4*)(S_bf + (size_t)(t * 4 + (r & 3)) * 128 + ch * 8);
      *(uint4*)&Awin[r][((ch ^ (r & 15)) & 15) * 8] = v;
    }
  }
  __syncthreads();

  // Per-lane B base (k-chunk-major WcT): chunk addr =
  // ((p*16 + ks*2 + half)*128 + nh*64 + nt*32 + l31)*8.
  const u16* wbase = WcT + (size_t)half * 1024 + (size_t)(nh * 64 + l31) * 8;
#pragma unroll
  for (int pj = 0; pj < 4; ++pj) {
    const int pi = ph * 4 + pj;
    const int shift = 4 * (7 - pi);               // A window row offset
    const u16* wp = wbase + (size_t)((P0 + pi) * 16) * 1024;
#pragma unroll
    for (int ks = 0; ks < 8; ++ks) {              // K = 128 = 8 steps of 16
      bf16x8 bfr[2];
      bfr[0] = *(const bf16x8*)(wp + (size_t)(ks * 2) * 1024);
      bfr[1] = *(const bf16x8*)(wp + (size_t)(ks * 2) * 1024 + 256);
      int kc = ks * 2 + half;
      bf16x8 af[2];
#pragma unroll
      for (int mt = 0; mt < 2; ++mt) {
        int r = mt * 32 + shift + l31;            // max 91
        af[mt] = *(const bf16x8*)&Awin[r][((kc ^ (r & 15)) & 15) * 8];
      }
#pragma unroll
      for (int mt = 0; mt < 2; ++mt)
#pragma unroll
        for (int nt = 0; nt < 2; ++nt)
          acc[mt][nt] = __builtin_amdgcn_mfma_f32_32x32x16_bf16(af[mt], bfr[nt], acc[mt][nt], 0, 0, 0);
    }
  }

  // Pair-reduce ph=0 + ph=1 (same nh) via LDS, then ph=1 stores the chunk.
  __syncthreads();                  // window reads done; reuse LDS as scratch
  if (ph == 0) {
#pragma unroll
    for (int mt = 0; mt < 2; ++mt)
#pragma unroll
      for (int nt = 0; nt < 2; ++nt)
#pragma unroll
        for (int rg = 0; rg < 16; ++rg) {
          int m = mt * 32 + (rg & 3) + 8 * (rg >> 2) + 4 * half;
          S2[nh][m][nt * 32 + l31] = acc[mt][nt][rg];   // bank = l31: 2-way, free
        }
  }
  __syncthreads();
  if (ph == 1) {
    float* op = partial + (size_t)blockIdx.y * 524288;
#pragma unroll
    for (int mt = 0; mt < 2; ++mt)
#pragma unroll
      for (int nt = 0; nt < 2; ++nt)
#pragma unroll
        for (int rg = 0; rg < 16; ++rg) {
          int m = mt * 32 + (rg & 3) + 8 * (rg >> 2) + 4 * half;
          int n = nh * 64 + nt * 32 + l31;
          op[(size_t)(m0 + m) * 128 + n] = acc[mt][nt][rg] + S2[nh][m][nt * 32 + l31];
        }
  }
}

// Reduce 8 partials + b_ctx -> sigmoid gate; gated = states(fp32)*gate; FC+sig+clip.
// 16 rows/block, float4 partial reads, W_fc staged [pp][h] chunk-XOR-swizzled,
// dot loop all-b128.
__global__ __launch_bounds__(256) void k_epilogue(const float* __restrict__ partial,
                                                  const float* __restrict__ states,
                                                  const float* __restrict__ b_ctx,
                                                  const float* __restrict__ W_fc,
                                                  const float* __restrict__ b_fc,
                                                  float* __restrict__ out_probs) {
  __shared__ float Wfc2[64][128];   // chunk c of row pp at pos c ^ (pp&31)
  __shared__ float gated[16][128];
  const int tid = threadIdx.x;
  const int row0 = blockIdx.x * 16;
  for (int it = 0; it < 8; ++it) {
    int i = it * 256 + tid;         // 64 rows x 32 float4 chunks
    int pp = i >> 5, c = i & 31;
    float4 v = *(const float4*)(W_fc + i * 4);
    *(float4*)&Wfc2[pp][((c ^ pp) & 31) * 4] = v;
  }
  for (int it = 0; it < 2; ++it) {
    int i = it * 256 + tid;         // 16 rows x 32 h-chunks = 512
    int lr = i >> 5, h0 = (i & 31) * 4;
    int sr = row0 + lr;
    float4 gp = *(const float4*)(b_ctx + h0);
#pragma unroll
    for (int c = 0; c < 8; ++c) {
      float4 pv = *(const float4*)(partial + (size_t)c * 524288 + (size_t)sr * 128 + h0);
      gp.x += pv.x; gp.y += pv.y; gp.z += pv.z; gp.w += pv.w;
    }
    float4 st = *(const float4*)(states + (size_t)sr * 128 + h0);
    float4 gv;
    gv.x = st.x * sigmoidf_(gp.x);
    gv.y = st.y * sigmoidf_(gp.y);
    gv.z = st.z * sigmoidf_(gp.z);
    gv.w = st.w * sigmoidf_(gp.w);
    *(float4*)&gated[lr][h0] = gv;
  }
  __syncthreads();
  for (int it = 0; it < 4; ++it) {
    int o = it * 256 + tid;         // 16 rows x 64 pp = 1024
    int lr = o >> 6, pp = o & 63;
    int sr = row0 + lr;
    float dot = 0.f;
#pragma unroll
    for (int i = 0; i < 32; ++i) {
      float4 g = *(const float4*)&gated[lr][i * 4];
      float4 wv = *(const float4*)&Wfc2[pp][((i ^ pp) & 31) * 4];
      dot += g.x * wv.x + g.y * wv.y + g.z * wv.z + g.w * wv.w;
    }
    float pv = sigmoidf_(dot + b_fc[pp]);
    pv = (pv > 0.001f) ? pv : 0.001f;
    pv = (pv < 0.999f) ? pv : 0.999f;
    int t = sr >> 2, b = sr & 3;
    out_probs[(b * 1024 + t) * 64 + pp] = pv;
  }
}

extern "C" void kernel_launch(void* const* d_in, const int* in_sizes, int n_in,
                              void* d_out, int out_size, void* d_ws, size_t ws_size,
                              hipStream_t stream) {
  const float* x     = (const float*)d_in[0];
  const float* W_ih  = (const float*)d_in[1];
  // d_in[2] = W_hh: unused (hidden state is always 0 in the reference)
  const float* b_ih  = (const float*)d_in[3];
  const float* b_hh  = (const float*)d_in[4];
  const float* W_ctx = (const float*)d_in[5];
  const float* b_ctx = (const float*)d_in[6];
  const float* W_fc  = (const float*)d_in[7];
  const float* b_fc  = (const float*)d_in[8];
  float* out = (float*)d_out;

  char* ws = (char*)d_ws;
  u16*   gi_bf   = (u16*)  (ws + 0);          // 3,145,728 B
  u16*   S_bf    = (u16*)  (ws + 3145728);    // 1,048,576 B
  u16*   WcT     = (u16*)  (ws + 4194304);    // 2,097,152 B
  float* partial = (float*)(ws + 6291456);    // 16,777,216 B
  // total ws used: 23,068,672 bytes

  k_front<<<320, 512, 0, stream>>>(x, W_ih, gi_bf, W_ctx, WcT);
  k_states<<<512, 256, 0, stream>>>(gi_bf, b_ih, b_hh, S_bf, out + 262144);
  k_gemm_ctx<<<dim3(64, 8), 256, 0, stream>>>(S_bf, WcT, partial);
  k_epilogue<<<256, 256, 0, stream>>>(partial, out + 262144, b_ctx, W_fc, b_fc, out);
}

// Round 5
// 120.390 us; speedup vs baseline: 1.0768x; 1.0029x over previous
//
#include <hip/hip_runtime.h>

// Problem constants: B=4, T=1024, F=500, H=128, P=64
// All external buffers fp32. Internal GEMMs bf16 (fp32 MFMA accum).
// out = [probs (B*T*P=262144), all_states (T*B*H=524288)] fp32
//
// ws layout:
//   gi_bf   [0,        3145728)  4096x384 bf16
//   S_bf    [3145728,  4194304)  4096x128 bf16 ([T,B,H] rows sr=t*4+b)
//   WcT     [4194304,  6291456)  64x16x128x8 bf16 (folded ctx weights,
//                                k-chunk-major: [p][kc][n][8k])
//   partial [6291456, 14680064)  4 x 4096x128 fp32 (ctx split-p partials)

typedef short bf16x8 __attribute__((ext_vector_type(8)));
typedef float f32x4 __attribute__((ext_vector_type(4)));
typedef float f32x16 __attribute__((ext_vector_type(16)));
typedef unsigned short u16;
typedef unsigned int u32;

__device__ __forceinline__ float bf2f(u16 u) {
  union { u32 i; float f; } v; v.i = ((u32)u) << 16; return v.f;
}
__device__ __forceinline__ u16 f2bf(float f) {
  union { float f; u32 i; } v; v.f = f;
  u32 u = v.i;
  return (u16)((u + 0x7FFFu + ((u >> 16) & 1u)) >> 16);
}
__device__ __forceinline__ u32 pack2(float a, float b) {
  return (u32)f2bf(a) | ((u32)f2bf(b) << 16);
}
__device__ __forceinline__ float sigmoidf_(float x) {
  return 1.0f / (1.0f + __expf(-x));
}

// Fused front kernel: blocks 0..191 run the gi GEMM (bx = bid%64, by = bid/64),
// blocks 192..319 run the W_ctx prep (hp = bid-192). Roles share one 48 KB
// LDS byte array (manual overlay) so gi keeps its occupancy.
__global__ __launch_bounds__(512, 4) void k_front(const float* __restrict__ x,
                                                  const float* __restrict__ W_ih,
                                                  u16* __restrict__ gi_bf,
                                                  const float* __restrict__ W_ctx,
                                                  u16* __restrict__ WcT) {
  __shared__ __align__(16) char smem[49152];
  const int tid = threadIdx.x;
  const int bid = blockIdx.x;

  if (bid < 192) {
    // ---------------- gi GEMM role ----------------
    typedef u16 AsmT[64][64];
    typedef u16 BsmT[128][64];
    AsmT* Asm = (AsmT*)smem;              // [2][64][64]  = 16 KB
    BsmT* Bsm = (BsmT*)(smem + 16384);    // [2][128][64] = 32 KB
    const int w = tid >> 6, lane = tid & 63;
    const int l15 = lane & 15, quad = lane >> 4;
    const int wm = (w & 1) * 32, wn = (w >> 1) * 32;
    const int m0 = (bid & 63) * 64;
    const int n0 = (bid >> 6) * 128;
    f32x4 acc[2][2];
    for (int i = 0; i < 2; ++i)
      for (int j = 0; j < 2; ++j) acc[i][j] = (f32x4){0.f, 0.f, 0.f, 0.f};

    uint4 ra, rb[2];
    auto cvt_load = [](const float* base, int k) -> uint4 {
      float4 a = make_float4(0.f, 0.f, 0.f, 0.f), b = a;
      if (k < 500)     a = *(const float4*)(base + k);
      if (k + 4 < 500) b = *(const float4*)(base + k + 4);
      uint4 o; o.x = pack2(a.x, a.y); o.y = pack2(a.z, a.w);
      o.z = pack2(b.x, b.y); o.w = pack2(b.z, b.w);
      return o;
    };
    auto load_step = [&](int s) {
      int kc = s * 64;
      {   // A: 64 rows x 8 chunks = 512, 1/thread
        int c = tid;
        ra = cvt_load(x + (size_t)(m0 + (c >> 3)) * 500, kc + (c & 7) * 8);
      }
#pragma unroll
      for (int j = 0; j < 2; ++j) {   // B: 128 rows x 8 chunks = 1024, 2/thread
        int c = j * 512 + tid;
        rb[j] = cvt_load(W_ih + (size_t)(n0 + (c >> 3)) * 500, kc + (c & 7) * 8);
      }
    };
    auto write_step = [&](int b) {
      {
        int c = tid;
        int r = c >> 3, pc = (c & 7) ^ (r & 7);
        *(uint4*)&Asm[b][r][pc * 8] = ra;
      }
#pragma unroll
      for (int j = 0; j < 2; ++j) {
        int c = j * 512 + tid;
        int r = c >> 3, pc = (c & 7) ^ (r & 7);
        *(uint4*)&Bsm[b][r][pc * 8] = rb[j];
      }
    };

    load_step(0); write_step(0); __syncthreads();
    for (int s = 0; s < 8; ++s) {
      int cur = s & 1;
      if (s < 7) load_step(s + 1);
#pragma unroll
      for (int kk = 0; kk < 2; ++kk) {
        int ch = kk * 4 + quad;
        bf16x8 af[2], bfr[2];
#pragma unroll
        for (int mt = 0; mt < 2; ++mt) {
          int r = wm + mt * 16 + l15;
          af[mt] = *(const bf16x8*)&Asm[cur][r][(ch ^ (r & 7)) * 8];
        }
#pragma unroll
        for (int nt = 0; nt < 2; ++nt) {
          int r = wn + nt * 16 + l15;
          bfr[nt] = *(const bf16x8*)&Bsm[cur][r][(ch ^ (r & 7)) * 8];
        }
#pragma unroll
        for (int mt = 0; mt < 2; ++mt)
#pragma unroll
          for (int nt = 0; nt < 2; ++nt)
            acc[mt][nt] = __builtin_amdgcn_mfma_f32_16x16x32_bf16(af[mt], bfr[nt], acc[mt][nt], 0, 0, 0);
      }
      if (s < 7) write_step((s + 1) & 1);
      __syncthreads();
    }
    for (int mt = 0; mt < 2; ++mt)
      for (int nt = 0; nt < 2; ++nt)
        for (int rg = 0; rg < 4; ++rg) {
          int m = m0 + wm + mt * 16 + quad * 4 + rg;   // C/D: row=(lane>>4)*4+reg
          int n = n0 + wn + nt * 16 + l15;             //      col=lane&15
          gi_bf[m * 384 + n] = f2bf(acc[mt][nt][rg]);
        }
  } else {
    // ---------------- prep role ----------------
    typedef float T2Row[68];
    T2Row* t2 = (T2Row*)smem;                 // [128][68] = 34816 B
    float* s1 = (float*)(smem + 34816);       // 512 B
    const int hp = bid - 192;
    const float* wrow = W_ctx + hp * 16384;
    // part2 -> LDS transpose buffer (2048 float4 / 512 thr = 4 iters)
    for (int it = 0; it < 4; ++it) {
      int i = it * 512 + tid;
      int j = i * 4;
      int h = j >> 6, q = j & 63;
      *(float4*)&t2[h][q] = *(const float4*)(wrow + 8192 + j);
    }
    // part1 row sums via wave reduce: wave w handles rows w, w+8, ...
    {
      const int w = tid >> 6, lane = tid & 63;
      for (int rr = w; rr < 128; rr += 8) {
        float v = wrow[rr * 64 + lane];
#pragma unroll
        for (int off = 32; off; off >>= 1) v += __shfl_down(v, off, 64);
        if (lane == 0) s1[rr] = v;
      }
    }
    __syncthreads();
    // store: 2048 (p, h0) pairs / 512 thr = 4 iters
    for (int it = 0; it < 4; ++it) {
      int i = it * 512 + tid;
      int p = i >> 5, h0 = (i & 31) * 4;
      float v0 = t2[h0 + 0][p], v1 = t2[h0 + 1][p];
      float v2 = t2[h0 + 2][p], v3 = t2[h0 + 3][p];
      if (p == 0) { v0 += s1[h0]; v1 += s1[h0 + 1]; v2 += s1[h0 + 2]; v3 += s1[h0 + 3]; }
      uint2 o; o.x = pack2(v0, v1); o.y = pack2(v2, v3);
      *(uint2*)(WcT + ((size_t)(p * 16 + (h0 >> 3)) * 128 + hp) * 8 + (h0 & 7)) = o;
    }
  }
}

// GRU gates with h=0: s = (1-sig(gz+bz)) * tanh(gn + sig(gr+br)*bn_hh).
// Vectorized x4 over h (uint2 bf16 loads, float4 stores).
__global__ void k_states(const u16* __restrict__ gi_bf,
                         const float* __restrict__ b_ih, const float* __restrict__ b_hh,
                         u16* __restrict__ S_bf, float* __restrict__ out_states) {
  int g = blockIdx.x * 256 + threadIdx.x;  // 131072 = 4096 rows x 32 h-groups
  int r = g >> 5, h0 = (g & 31) * 4;
  const u16* gr = gi_bf + r * 384;
  uint2 ur = *(const uint2*)(gr + h0);
  uint2 uz = *(const uint2*)(gr + 128 + h0);
  uint2 un = *(const uint2*)(gr + 256 + h0);
  float4 bir = *(const float4*)(b_ih + h0);
  float4 biz = *(const float4*)(b_ih + 128 + h0);
  float4 bin = *(const float4*)(b_ih + 256 + h0);
  float4 bhr = *(const float4*)(b_hh + h0);
  float4 bhz = *(const float4*)(b_hh + 128 + h0);
  float4 bhn = *(const float4*)(b_hh + 256 + h0);
  float xr[4] = { bf2f((u16)ur.x) + bir.x + bhr.x, bf2f((u16)(ur.x >> 16)) + bir.y + bhr.y,
                  bf2f((u16)ur.y) + bir.z + bhr.z, bf2f((u16)(ur.y >> 16)) + bir.w + bhr.w };
  float xz[4] = { bf2f((u16)uz.x) + biz.x + bhz.x, bf2f((u16)(uz.x >> 16)) + biz.y + bhz.y,
                  bf2f((u16)uz.y) + biz.z + bhz.z, bf2f((u16)(uz.y >> 16)) + biz.w + bhz.w };
  float xn[4] = { bf2f((u16)un.x) + bin.x, bf2f((u16)(un.x >> 16)) + bin.y,
                  bf2f((u16)un.y) + bin.z, bf2f((u16)(un.y >> 16)) + bin.w };
  float bn[4] = { bhn.x, bhn.y, bhn.z, bhn.w };
  float s[4];
#pragma unroll
  for (int j = 0; j < 4; ++j) {
    float rg = sigmoidf_(xr[j]);
    float zg = sigmoidf_(xz[j]);
    float n = tanhf(xn[j] + rg * bn[j]);
    s[j] = (1.f - zg) * n;
  }
  int b = r >> 10, t = r & 1023;
  size_t o = (size_t)(t * 4 + b) * 128 + h0;
  uint2 sb; sb.x = pack2(s[0], s[1]); sb.y = pack2(s[2], s[3]);
  *(uint2*)(S_bf + o) = sb;
  float4 so = make_float4(s[0], s[1], s[2], s[3]);
  *(float4*)(out_states + o) = so;
}

// Context GEMM v6: partial[chunk][m][h'] = sum_{p in chunk of 16} Wc_p @ s[max(t-p,0),b].
// 32x32x16 MFMA, wave-tile 64m x 64n (0.5 ds_read/MFMA, 0.5 KB B-load/MFMA).
// v6 vs v5: 4 p-chunks of 16 (halves the partial round-trip 16.8->8.4 MB
// each way). Grid (64 m, 2 n-halves, 4 p-chunks) = 512 blocks, 256 thr
// (4 waves). Wave w computes 4 p's (pi = w*4+pj) over the SAME 64m x 64n
// tile; 4-way fp32 reduce via LDS (waves 1-3 store 48 KB scratch, wave 0
// sums + stores the chunk). Per-wave work identical to v5 (32 barrier-free
// K-iters), occupancy identical (2 blocks/CU, 8 waves/CU = 2/SIMD).
// A window: 124 rows (31 KB), swizzle pos = ch ^ (r & 15); LDS union 48 KB.
// A frag (32x32x16): lane l = row l&31, k = (l>>5)*8+j; B: col l&31, same k.
// C/D: col = lane&31, row = (reg&3) + 8*(reg>>2) + 4*(lane>>5).
__global__ __launch_bounds__(256, 2) void k_gemm_ctx(const u16* __restrict__ S_bf,
                                                     const u16* __restrict__ WcT,
                                                     float* __restrict__ partial) {
  __shared__ __align__(16) char smem[49152];
  u16 (*Awin)[128] = (u16(*)[128])smem;          // [124][128] u16 = 31744 B
  float (*S3)[64][64] = (float(*)[64][64])smem;  // [3][64][64] f32 = 49152 B
  const int tid = threadIdx.x;
  const int w = tid >> 6, lane = tid & 63;
  const int l31 = lane & 31, half = lane >> 5;
  const int m0 = blockIdx.x * 64;
  const int n0 = blockIdx.y * 64;
  const int P0 = blockIdx.z * 16;
  const int tlo = (m0 >> 2) - P0 - 15;  // may be negative; rows clamp to s[0]
  f32x16 acc[2][2];                 // [mt][nt]
#pragma unroll
  for (int i = 0; i < 16; ++i) {
    acc[0][0][i] = 0.f; acc[0][1][i] = 0.f;
    acc[1][0][i] = 0.f; acc[1][1][i] = 0.f;
  }

  // Stage A window: row r holds s[max(tlo + (r>>2), 0), b=r&3][:], swizzled
  // chunk pos = ch ^ (r & 15). 124 rows x 16 chunks = 1984 uint4.
  for (int it = 0; it < 8; ++it) {
    int idx = it * 256 + tid;
    if (idx < 1984) {
      int r = idx >> 4, ch = idx & 15;
      int t = tlo + (r >> 2); if (t < 0) t = 0;
      uint4 v = *(const uint4*)(S_bf + (size_t)(t * 4 + (r & 3)) * 128 + ch * 8);
      *(uint4*)&Awin[r][((ch ^ (r & 15)) & 15) * 8] = v;
    }
  }
  __syncthreads();

  // Per-lane B base (k-chunk-major WcT): chunk addr =
  // ((p*16 + ks*2 + half)*128 + n0 + nt*32 + l31)*8.
  const u16* wbase = WcT + (size_t)half * 1024 + (size_t)(n0 + l31) * 8;
#pragma unroll
  for (int pj = 0; pj < 4; ++pj) {
    const int pi = w * 4 + pj;                    // p - P0, 0..15
    const int shift = 4 * (15 - pi);              // A window row offset
    const u16* wp = wbase + (size_t)((P0 + pi) * 16) * 1024;
#pragma unroll
    for (int ks = 0; ks < 8; ++ks) {              // K = 128 = 8 steps of 16
      bf16x8 bfr[2];
      bfr[0] = *(const bf16x8*)(wp + (size_t)(ks * 2) * 1024);
      bfr[1] = *(const bf16x8*)(wp + (size_t)(ks * 2) * 1024 + 256);
      int kc = ks * 2 + half;
      bf16x8 af[2];
#pragma unroll
      for (int mt = 0; mt < 2; ++mt) {
        int r = mt * 32 + shift + l31;            // max 123
        af[mt] = *(const bf16x8*)&Awin[r][((kc ^ (r & 15)) & 15) * 8];
      }
#pragma unroll
      for (int mt = 0; mt < 2; ++mt)
#pragma unroll
        for (int nt = 0; nt < 2; ++nt)
          acc[mt][nt] = __builtin_amdgcn_mfma_f32_32x32x16_bf16(af[mt], bfr[nt], acc[mt][nt], 0, 0, 0);
    }
  }

  // 4-way reduce: waves 1..3 store accs; wave 0 sums + stores the chunk.
  __syncthreads();                  // window reads done; reuse LDS as scratch
  if (w > 0) {
#pragma unroll
    for (int mt = 0; mt < 2; ++mt)
#pragma unroll
      for (int nt = 0; nt < 2; ++nt)
#pragma unroll
        for (int rg = 0; rg < 16; ++rg) {
          int m = mt * 32 + (rg & 3) + 8 * (rg >> 2) + 4 * half;
          S3[w - 1][m][nt * 32 + l31] = acc[mt][nt][rg];  // bank=l31: 2-way, free
        }
  }
  __syncthreads();
  if (w == 0) {
    float* op = partial + (size_t)blockIdx.z * 524288;
#pragma unroll
    for (int mt = 0; mt < 2; ++mt)
#pragma unroll
      for (int nt = 0; nt < 2; ++nt)
#pragma unroll
        for (int rg = 0; rg < 16; ++rg) {
          int m = mt * 32 + (rg & 3) + 8 * (rg >> 2) + 4 * half;
          int nl = nt * 32 + l31;
          float v = acc[mt][nt][rg] + S3[0][m][nl] + S3[1][m][nl] + S3[2][m][nl];
          op[(size_t)(m0 + m) * 128 + n0 + nl] = v;
        }
  }
}

// Reduce 4 partials + b_ctx -> sigmoid gate; gated = states(fp32)*gate; FC+sig+clip.
// 16 rows/block, float4 partial reads, W_fc staged [pp][h] chunk-XOR-swizzled,
// dot loop all-b128.
__global__ __launch_bounds__(256) void k_epilogue(const float* __restrict__ partial,
                                                  const float* __restrict__ states,
                                                  const float* __restrict__ b_ctx,
                                                  const float* __restrict__ W_fc,
                                                  const float* __restrict__ b_fc,
                                                  float* __restrict__ out_probs) {
  __shared__ float Wfc2[64][128];   // chunk c of row pp at pos c ^ (pp&31)
  __shared__ float gated[16][128];
  const int tid = threadIdx.x;
  const int row0 = blockIdx.x * 16;
  for (int it = 0; it < 8; ++it) {
    int i = it * 256 + tid;         // 64 rows x 32 float4 chunks
    int pp = i >> 5, c = i & 31;
    float4 v = *(const float4*)(W_fc + i * 4);
    *(float4*)&Wfc2[pp][((c ^ pp) & 31) * 4] = v;
  }
  for (int it = 0; it < 2; ++it) {
    int i = it * 256 + tid;         // 16 rows x 32 h-chunks = 512
    int lr = i >> 5, h0 = (i & 31) * 4;
    int sr = row0 + lr;
    float4 gp = *(const float4*)(b_ctx + h0);
#pragma unroll
    for (int c = 0; c < 4; ++c) {
      float4 pv = *(const float4*)(partial + (size_t)c * 524288 + (size_t)sr * 128 + h0);
      gp.x += pv.x; gp.y += pv.y; gp.z += pv.z; gp.w += pv.w;
    }
    float4 st = *(const float4*)(states + (size_t)sr * 128 + h0);
    float4 gv;
    gv.x = st.x * sigmoidf_(gp.x);
    gv.y = st.y * sigmoidf_(gp.y);
    gv.z = st.z * sigmoidf_(gp.z);
    gv.w = st.w * sigmoidf_(gp.w);
    *(float4*)&gated[lr][h0] = gv;
  }
  __syncthreads();
  for (int it = 0; it < 4; ++it) {
    int o = it * 256 + tid;         // 16 rows x 64 pp = 1024
    int lr = o >> 6, pp = o & 63;
    int sr = row0 + lr;
    float dot = 0.f;
#pragma unroll
    for (int i = 0; i < 32; ++i) {
      float4 g = *(const float4*)&gated[lr][i * 4];
      float4 wv = *(const float4*)&Wfc2[pp][((i ^ pp) & 31) * 4];
      dot += g.x * wv.x + g.y * wv.y + g.z * wv.z + g.w * wv.w;
    }
    float pv = sigmoidf_(dot + b_fc[pp]);
    pv = (pv > 0.001f) ? pv : 0.001f;
    pv = (pv < 0.999f) ? pv : 0.999f;
    int t = sr >> 2, b = sr & 3;
    out_probs[(b * 1024 + t) * 64 + pp] = pv;
  }
}

extern "C" void kernel_launch(void* const* d_in, const int* in_sizes, int n_in,
                              void* d_out, int out_size, void* d_ws, size_t ws_size,
                              hipStream_t stream) {
  const float* x     = (const float*)d_in[0];
  const float* W_ih  = (const float*)d_in[1];
  // d_in[2] = W_hh: unused (hidden state is always 0 in the reference)
  const float* b_ih  = (const float*)d_in[3];
  const float* b_hh  = (const float*)d_in[4];
  const float* W_ctx = (const float*)d_in[5];
  const float* b_ctx = (const float*)d_in[6];
  const float* W_fc  = (const float*)d_in[7];
  const float* b_fc  = (const float*)d_in[8];
  float* out = (float*)d_out;

  char* ws = (char*)d_ws;
  u16*   gi_bf   = (u16*)  (ws + 0);          // 3,145,728 B
  u16*   S_bf    = (u16*)  (ws + 3145728);    // 1,048,576 B
  u16*   WcT     = (u16*)  (ws + 4194304);    // 2,097,152 B
  float* partial = (float*)(ws + 6291456);    // 8,388,608 B
  // total ws used: 14,680,064 bytes

  k_front<<<320, 512, 0, stream>>>(x, W_ih, gi_bf, W_ctx, WcT);
  k_states<<<512, 256, 0, stream>>>(gi_bf, b_ih, b_hh, S_bf, out + 262144);
  k_gemm_ctx<<<dim3(64, 2, 4), 256, 0, stream>>>(S_bf, WcT, partial);
  k_epilogue<<<256, 256, 0, stream>>>(partial, out + 262144, b_ctx, W_fc, b_fc, out);
}

// Round 6
// 120.076 us; speedup vs baseline: 1.0796x; 1.0026x over previous
//
#include <hip/hip_runtime.h>

// Problem constants: B=4, T=1024, F=500, H=128, P=64
// All external buffers fp32. Internal GEMMs bf16 (fp32 MFMA accum).
// out = [probs (B*T*P=262144), all_states (T*B*H=524288)] fp32
//
// ws layout:
//   gi_bf   [0,        3145728)  4096x384 bf16
//   S_bf    [3145728,  4194304)  4096x128 bf16 ([T,B,H] rows sr=t*4+b)
//   WcT     [4194304,  6291456)  64x16x128x8 bf16 (folded ctx weights,
//                                k-chunk-major: [p][kc][n][8k])
//   partial [6291456, 14680064)  4 x 4096x128 fp32 (ctx split-p partials)

typedef short bf16x8 __attribute__((ext_vector_type(8)));
typedef float f32x4 __attribute__((ext_vector_type(4)));
typedef float f32x16 __attribute__((ext_vector_type(16)));
typedef unsigned short u16;
typedef unsigned int u32;

__device__ __forceinline__ float bf2f(u16 u) {
  union { u32 i; float f; } v; v.i = ((u32)u) << 16; return v.f;
}
__device__ __forceinline__ u16 f2bf(float f) {
  union { float f; u32 i; } v; v.f = f;
  u32 u = v.i;
  return (u16)((u + 0x7FFFu + ((u >> 16) & 1u)) >> 16);
}
__device__ __forceinline__ u32 pack2(float a, float b) {
  return (u32)f2bf(a) | ((u32)f2bf(b) << 16);
}
__device__ __forceinline__ float sigmoidf_(float x) {
  return 1.0f / (1.0f + __expf(-x));
}

// Fused front kernel: blocks 0..191 run the gi GEMM (bx = bid%64, by = bid/64),
// blocks 192..319 run the W_ctx prep (hp = bid-192). Roles share one 48 KB
// LDS byte array (manual overlay) so gi keeps its occupancy.
__global__ __launch_bounds__(512, 4) void k_front(const float* __restrict__ x,
                                                  const float* __restrict__ W_ih,
                                                  u16* __restrict__ gi_bf,
                                                  const float* __restrict__ W_ctx,
                                                  u16* __restrict__ WcT) {
  __shared__ __align__(16) char smem[49152];
  const int tid = threadIdx.x;
  const int bid = blockIdx.x;

  if (bid < 192) {
    // ---------------- gi GEMM role ----------------
    typedef u16 AsmT[64][64];
    typedef u16 BsmT[128][64];
    AsmT* Asm = (AsmT*)smem;              // [2][64][64]  = 16 KB
    BsmT* Bsm = (BsmT*)(smem + 16384);    // [2][128][64] = 32 KB
    const int w = tid >> 6, lane = tid & 63;
    const int l15 = lane & 15, quad = lane >> 4;
    const int wm = (w & 1) * 32, wn = (w >> 1) * 32;
    const int m0 = (bid & 63) * 64;
    const int n0 = (bid >> 6) * 128;
    f32x4 acc[2][2];
    for (int i = 0; i < 2; ++i)
      for (int j = 0; j < 2; ++j) acc[i][j] = (f32x4){0.f, 0.f, 0.f, 0.f};

    uint4 ra, rb[2];
    auto cvt_load = [](const float* base, int k) -> uint4 {
      float4 a = make_float4(0.f, 0.f, 0.f, 0.f), b = a;
      if (k < 500)     a = *(const float4*)(base + k);
      if (k + 4 < 500) b = *(const float4*)(base + k + 4);
      uint4 o; o.x = pack2(a.x, a.y); o.y = pack2(a.z, a.w);
      o.z = pack2(b.x, b.y); o.w = pack2(b.z, b.w);
      return o;
    };
    auto load_step = [&](int s) {
      int kc = s * 64;
      {   // A: 64 rows x 8 chunks = 512, 1/thread
        int c = tid;
        ra = cvt_load(x + (size_t)(m0 + (c >> 3)) * 500, kc + (c & 7) * 8);
      }
#pragma unroll
      for (int j = 0; j < 2; ++j) {   // B: 128 rows x 8 chunks = 1024, 2/thread
        int c = j * 512 + tid;
        rb[j] = cvt_load(W_ih + (size_t)(n0 + (c >> 3)) * 500, kc + (c & 7) * 8);
      }
    };
    auto write_step = [&](int b) {
      {
        int c = tid;
        int r = c >> 3, pc = (c & 7) ^ (r & 7);
        *(uint4*)&Asm[b][r][pc * 8] = ra;
      }
#pragma unroll
      for (int j = 0; j < 2; ++j) {
        int c = j * 512 + tid;
        int r = c >> 3, pc = (c & 7) ^ (r & 7);
        *(uint4*)&Bsm[b][r][pc * 8] = rb[j];
      }
    };

    load_step(0); write_step(0); __syncthreads();
    for (int s = 0; s < 8; ++s) {
      int cur = s & 1;
      if (s < 7) load_step(s + 1);
#pragma unroll
      for (int kk = 0; kk < 2; ++kk) {
        int ch = kk * 4 + quad;
        bf16x8 af[2], bfr[2];
#pragma unroll
        for (int mt = 0; mt < 2; ++mt) {
          int r = wm + mt * 16 + l15;
          af[mt] = *(const bf16x8*)&Asm[cur][r][(ch ^ (r & 7)) * 8];
        }
#pragma unroll
        for (int nt = 0; nt < 2; ++nt) {
          int r = wn + nt * 16 + l15;
          bfr[nt] = *(const bf16x8*)&Bsm[cur][r][(ch ^ (r & 7)) * 8];
        }
#pragma unroll
        for (int mt = 0; mt < 2; ++mt)
#pragma unroll
          for (int nt = 0; nt < 2; ++nt)
            acc[mt][nt] = __builtin_amdgcn_mfma_f32_16x16x32_bf16(af[mt], bfr[nt], acc[mt][nt], 0, 0, 0);
      }
      if (s < 7) write_step((s + 1) & 1);
      __syncthreads();
    }
    for (int mt = 0; mt < 2; ++mt)
      for (int nt = 0; nt < 2; ++nt)
        for (int rg = 0; rg < 4; ++rg) {
          int m = m0 + wm + mt * 16 + quad * 4 + rg;   // C/D: row=(lane>>4)*4+reg
          int n = n0 + wn + nt * 16 + l15;             //      col=lane&15
          gi_bf[m * 384 + n] = f2bf(acc[mt][nt][rg]);
        }
  } else {
    // ---------------- prep role ----------------
    typedef float T2Row[68];
    T2Row* t2 = (T2Row*)smem;                 // [128][68] = 34816 B
    float* s1 = (float*)(smem + 34816);       // 512 B
    const int hp = bid - 192;
    const float* wrow = W_ctx + hp * 16384;
    // part2 -> LDS transpose buffer (2048 float4 / 512 thr = 4 iters)
    for (int it = 0; it < 4; ++it) {
      int i = it * 512 + tid;
      int j = i * 4;
      int h = j >> 6, q = j & 63;
      *(float4*)&t2[h][q] = *(const float4*)(wrow + 8192 + j);
    }
    // part1 row sums via wave reduce: wave w handles rows w, w+8, ...
    {
      const int w = tid >> 6, lane = tid & 63;
      for (int rr = w; rr < 128; rr += 8) {
        float v = wrow[rr * 64 + lane];
#pragma unroll
        for (int off = 32; off; off >>= 1) v += __shfl_down(v, off, 64);
        if (lane == 0) s1[rr] = v;
      }
    }
    __syncthreads();
    // store: 2048 (p, h0) pairs / 512 thr = 4 iters
    for (int it = 0; it < 4; ++it) {
      int i = it * 512 + tid;
      int p = i >> 5, h0 = (i & 31) * 4;
      float v0 = t2[h0 + 0][p], v1 = t2[h0 + 1][p];
      float v2 = t2[h0 + 2][p], v3 = t2[h0 + 3][p];
      if (p == 0) { v0 += s1[h0]; v1 += s1[h0 + 1]; v2 += s1[h0 + 2]; v3 += s1[h0 + 3]; }
      uint2 o; o.x = pack2(v0, v1); o.y = pack2(v2, v3);
      *(uint2*)(WcT + ((size_t)(p * 16 + (h0 >> 3)) * 128 + hp) * 8 + (h0 & 7)) = o;
    }
  }
}

// GRU gates with h=0: s = (1-sig(gz+bz)) * tanh(gn + sig(gr+br)*bn_hh).
// Vectorized x4 over h (uint2 bf16 loads, float4 stores).
__global__ void k_states(const u16* __restrict__ gi_bf,
                         const float* __restrict__ b_ih, const float* __restrict__ b_hh,
                         u16* __restrict__ S_bf, float* __restrict__ out_states) {
  int g = blockIdx.x * 256 + threadIdx.x;  // 131072 = 4096 rows x 32 h-groups
  int r = g >> 5, h0 = (g & 31) * 4;
  const u16* gr = gi_bf + r * 384;
  uint2 ur = *(const uint2*)(gr + h0);
  uint2 uz = *(const uint2*)(gr + 128 + h0);
  uint2 un = *(const uint2*)(gr + 256 + h0);
  float4 bir = *(const float4*)(b_ih + h0);
  float4 biz = *(const float4*)(b_ih + 128 + h0);
  float4 bin = *(const float4*)(b_ih + 256 + h0);
  float4 bhr = *(const float4*)(b_hh + h0);
  float4 bhz = *(const float4*)(b_hh + 128 + h0);
  float4 bhn = *(const float4*)(b_hh + 256 + h0);
  float xr[4] = { bf2f((u16)ur.x) + bir.x + bhr.x, bf2f((u16)(ur.x >> 16)) + bir.y + bhr.y,
                  bf2f((u16)ur.y) + bir.z + bhr.z, bf2f((u16)(ur.y >> 16)) + bir.w + bhr.w };
  float xz[4] = { bf2f((u16)uz.x) + biz.x + bhz.x, bf2f((u16)(uz.x >> 16)) + biz.y + bhz.y,
                  bf2f((u16)uz.y) + biz.z + bhz.z, bf2f((u16)(uz.y >> 16)) + biz.w + bhz.w };
  float xn[4] = { bf2f((u16)un.x) + bin.x, bf2f((u16)(un.x >> 16)) + bin.y,
                  bf2f((u16)un.y) + bin.z, bf2f((u16)(un.y >> 16)) + bin.w };
  float bn[4] = { bhn.x, bhn.y, bhn.z, bhn.w };
  float s[4];
#pragma unroll
  for (int j = 0; j < 4; ++j) {
    float rg = sigmoidf_(xr[j]);
    float zg = sigmoidf_(xz[j]);
    float n = tanhf(xn[j] + rg * bn[j]);
    s[j] = (1.f - zg) * n;
  }
  int b = r >> 10, t = r & 1023;
  size_t o = (size_t)(t * 4 + b) * 128 + h0;
  uint2 sb; sb.x = pack2(s[0], s[1]); sb.y = pack2(s[2], s[3]);
  *(uint2*)(S_bf + o) = sb;
  float4 so = make_float4(s[0], s[1], s[2], s[3]);
  *(float4*)(out_states + o) = so;
}

// Context GEMM v6: partial[chunk][m][h'] = sum_{p in chunk of 16} Wc_p @ s[max(t-p,0),b].
// 32x32x16 MFMA, wave-tile 64m x 64n (0.5 ds_read/MFMA, 0.5 KB B-load/MFMA).
// Grid (64 m, 2 n-halves, 4 p-chunks) = 512 blocks, 256 thr (4 waves).
// Wave w computes 4 p's (pi = w*4+pj) over the SAME 64m x 64n tile; 4-way
// fp32 reduce via LDS (waves 1-3 store 48 KB scratch, wave 0 sums + stores).
// 2 blocks/CU, 8 waves/CU (2/SIMD). A window: 124 rows (31 KB), swizzle
// pos = ch ^ (r & 15); LDS union 48 KB.
// A frag (32x32x16): lane l = row l&31, k = (l>>5)*8+j; B: col l&31, same k.
// C/D: col = lane&31, row = (reg&3) + 8*(reg>>2) + 4*(lane>>5).
__global__ __launch_bounds__(256, 2) void k_gemm_ctx(const u16* __restrict__ S_bf,
                                                     const u16* __restrict__ WcT,
                                                     float* __restrict__ partial) {
  __shared__ __align__(16) char smem[49152];
  u16 (*Awin)[128] = (u16(*)[128])smem;          // [124][128] u16 = 31744 B
  float (*S3)[64][64] = (float(*)[64][64])smem;  // [3][64][64] f32 = 49152 B
  const int tid = threadIdx.x;
  const int w = tid >> 6, lane = tid & 63;
  const int l31 = lane & 31, half = lane >> 5;
  const int m0 = blockIdx.x * 64;
  const int n0 = blockIdx.y * 64;
  const int P0 = blockIdx.z * 16;
  const int tlo = (m0 >> 2) - P0 - 15;  // may be negative; rows clamp to s[0]
  f32x16 acc[2][2];                 // [mt][nt]
#pragma unroll
  for (int i = 0; i < 16; ++i) {
    acc[0][0][i] = 0.f; acc[0][1][i] = 0.f;
    acc[1][0][i] = 0.f; acc[1][1][i] = 0.f;
  }

  // Stage A window: row r holds s[max(tlo + (r>>2), 0), b=r&3][:], swizzled
  // chunk pos = ch ^ (r & 15). 124 rows x 16 chunks = 1984 uint4.
  for (int it = 0; it < 8; ++it) {
    int idx = it * 256 + tid;
    if (idx < 1984) {
      int r = idx >> 4, ch = idx & 15;
      int t = tlo + (r >> 2); if (t < 0) t = 0;
      uint4 v = *(const uint4*)(S_bf + (size_t)(t * 4 + (r & 3)) * 128 + ch * 8);
      *(uint4*)&Awin[r][((ch ^ (r & 15)) & 15) * 8] = v;
    }
  }
  __syncthreads();

  // Per-lane B base (k-chunk-major WcT): chunk addr =
  // ((p*16 + ks*2 + half)*128 + n0 + nt*32 + l31)*8.
  const u16* wbase = WcT + (size_t)half * 1024 + (size_t)(n0 + l31) * 8;
#pragma unroll
  for (int pj = 0; pj < 4; ++pj) {
    const int pi = w * 4 + pj;                    // p - P0, 0..15
    const int shift = 4 * (15 - pi);              // A window row offset
    const u16* wp = wbase + (size_t)((P0 + pi) * 16) * 1024;
#pragma unroll
    for (int ks = 0; ks < 8; ++ks) {              // K = 128 = 8 steps of 16
      bf16x8 bfr[2];
      bfr[0] = *(const bf16x8*)(wp + (size_t)(ks * 2) * 1024);
      bfr[1] = *(const bf16x8*)(wp + (size_t)(ks * 2) * 1024 + 256);
      int kc = ks * 2 + half;
      bf16x8 af[2];
#pragma unroll
      for (int mt = 0; mt < 2; ++mt) {
        int r = mt * 32 + shift + l31;            // max 123
        af[mt] = *(const bf16x8*)&Awin[r][((kc ^ (r & 15)) & 15) * 8];
      }
#pragma unroll
      for (int mt = 0; mt < 2; ++mt)
#pragma unroll
        for (int nt = 0; nt < 2; ++nt)
          acc[mt][nt] = __builtin_amdgcn_mfma_f32_32x32x16_bf16(af[mt], bfr[nt], acc[mt][nt], 0, 0, 0);
    }
  }

  // 4-way reduce: waves 1..3 store accs; wave 0 sums + stores the chunk.
  __syncthreads();                  // window reads done; reuse LDS as scratch
  if (w > 0) {
#pragma unroll
    for (int mt = 0; mt < 2; ++mt)
#pragma unroll
      for (int nt = 0; nt < 2; ++nt)
#pragma unroll
        for (int rg = 0; rg < 16; ++rg) {
          int m = mt * 32 + (rg & 3) + 8 * (rg >> 2) + 4 * half;
          S3[w - 1][m][nt * 32 + l31] = acc[mt][nt][rg];  // bank=l31: 2-way, free
        }
  }
  __syncthreads();
  if (w == 0) {
    float* op = partial + (size_t)blockIdx.z * 524288;
#pragma unroll
    for (int mt = 0; mt < 2; ++mt)
#pragma unroll
      for (int nt = 0; nt < 2; ++nt)
#pragma unroll
        for (int rg = 0; rg < 16; ++rg) {
          int m = mt * 32 + (rg & 3) + 8 * (rg >> 2) + 4 * half;
          int nl = nt * 32 + l31;
          float v = acc[mt][nt][rg] + S3[0][m][nl] + S3[1][m][nl] + S3[2][m][nl];
          op[(size_t)(m0 + m) * 128 + n0 + nl] = v;
        }
  }
}

// Epilogue v4: reduce 4 partials + b_ctx -> sigmoid gate; gated = states*gate;
// FC+sig+clip. 512 thr, 16 rows/block, grid 256. Each thread owns W_fc row
// pp = tid&63 in REGISTERS (32 f32x4, statically indexed); wave-uniform lr
// makes the gated[] read a broadcast (1 LDS transaction, conflict-free).
// Phase-2 LDS cost drops ~24x vs the LDS-dot version; dot order unchanged
// (ascending i, same pairing) -> bit-identical output.
__global__ __launch_bounds__(512) void k_epilogue(const float* __restrict__ partial,
                                                  const float* __restrict__ states,
                                                  const float* __restrict__ b_ctx,
                                                  const float* __restrict__ W_fc,
                                                  const float* __restrict__ b_fc,
                                                  float* __restrict__ out_probs) {
  __shared__ float gated[16][128];
  const int tid = threadIdx.x;
  const int row0 = blockIdx.x * 16;
  const int pp = tid & 63, lrg = tid >> 6;   // 8 lr-groups of 2 rows

  // W_fc row pp -> registers (W_fc is 32 KB, L2-resident; 16B/lane gather).
  f32x4 wreg[32];
#pragma unroll
  for (int i = 0; i < 32; ++i)
    wreg[i] = *(const f32x4*)(W_fc + (size_t)pp * 128 + i * 4);
  const float bfc = b_fc[pp];

  // Phase 1: gate + gated, 16 rows x 32 h-chunks = 512 = one item/thread.
  {
    int lr = tid >> 5, h0 = (tid & 31) * 4;
    int sr = row0 + lr;
    float4 gp = *(const float4*)(b_ctx + h0);
#pragma unroll
    for (int c = 0; c < 4; ++c) {
      float4 pv = *(const float4*)(partial + (size_t)c * 524288 + (size_t)sr * 128 + h0);
      gp.x += pv.x; gp.y += pv.y; gp.z += pv.z; gp.w += pv.w;
    }
    float4 st = *(const float4*)(states + (size_t)sr * 128 + h0);
    float4 gv;
    gv.x = st.x * sigmoidf_(gp.x);
    gv.y = st.y * sigmoidf_(gp.y);
    gv.z = st.z * sigmoidf_(gp.z);
    gv.w = st.w * sigmoidf_(gp.w);
    *(float4*)&gated[lr][h0] = gv;
  }
  __syncthreads();

  // Phase 2: per thread 2 rows; g-reads are wave-broadcast, W from regs.
#pragma unroll
  for (int q = 0; q < 2; ++q) {
    int lr = lrg * 2 + q;
    int sr = row0 + lr;
    float dot = 0.f;
#pragma unroll
    for (int i = 0; i < 32; ++i) {
      f32x4 g = *(const f32x4*)&gated[lr][i * 4];
      dot += g.x * wreg[i].x + g.y * wreg[i].y + g.z * wreg[i].z + g.w * wreg[i].w;
    }
    float pv = sigmoidf_(dot + bfc);
    pv = (pv > 0.001f) ? pv : 0.001f;
    pv = (pv < 0.999f) ? pv : 0.999f;
    int t = sr >> 2, b = sr & 3;
    out_probs[(b * 1024 + t) * 64 + pp] = pv;
  }
}

extern "C" void kernel_launch(void* const* d_in, const int* in_sizes, int n_in,
                              void* d_out, int out_size, void* d_ws, size_t ws_size,
                              hipStream_t stream) {
  const float* x     = (const float*)d_in[0];
  const float* W_ih  = (const float*)d_in[1];
  // d_in[2] = W_hh: unused (hidden state is always 0 in the reference)
  const float* b_ih  = (const float*)d_in[3];
  const float* b_hh  = (const float*)d_in[4];
  const float* W_ctx = (const float*)d_in[5];
  const float* b_ctx = (const float*)d_in[6];
  const float* W_fc  = (const float*)d_in[7];
  const float* b_fc  = (const float*)d_in[8];
  float* out = (float*)d_out;

  char* ws = (char*)d_ws;
  u16*   gi_bf   = (u16*)  (ws + 0);          // 3,145,728 B
  u16*   S_bf    = (u16*)  (ws + 3145728);    // 1,048,576 B
  u16*   WcT     = (u16*)  (ws + 4194304);    // 2,097,152 B
  float* partial = (float*)(ws + 6291456);    // 8,388,608 B
  // total ws used: 14,680,064 bytes

  k_front<<<320, 512, 0, stream>>>(x, W_ih, gi_bf, W_ctx, WcT);
  k_states<<<512, 256, 0, stream>>>(gi_bf, b_ih, b_hh, S_bf, out + 262144);
  k_gemm_ctx<<<dim3(64, 2, 4), 256, 0, stream>>>(S_bf, WcT, partial);
  k_epilogue<<<256, 512, 0, stream>>>(partial, out + 262144, b_ctx, W_fc, b_fc, out);
}